// Round 8
// baseline (34.759 us; speedup 1.0000x reference)
//
#include <hip/hip_runtime.h>

// ConcatAttention: B=4, SQ=SK=256, DQ=DK=DV=256, D=512
// score[b,q,k] = sum_h W2[h]*leaky(q_h+k_h+b1),  leaky(x)=0.505x+0.495|x|
//   => score = qlin[q] + klin[k] + 0.495*sum_h W2[h]*|q_h + (k_h+b1)|
//
// Kernel A (256 blk x 512 thr): split-bf16 MFMA GEMMs (A*B^T, row-major).
//   blk<128 : hh[q][h] = Q @ W1[:, :256]^T           (fp32 out)
//   blk>=128: kT2[hp][k] = packed-bf16 (W1k @ K^T + b1)
// Kernel B (256 blk x 512 thr): block=(b, 4 q-rows).
//   NEW: masked-column compaction. Block builds kidx[nk] (active cols) via
//   ballot+prefix; score loop runs ncg=ceil(nk/64) column-groups (1 col per
//   lane per group) -> VALU scales with active columns (~50%). PV iterates
//   compacted k (V row reads stay coalesced). Scores scattered to att.
//
// ws: hh [1024][512] f32, kT2 [256][1024] u32
#define HH_OFF 0
#define KT_OFF (1024 * 512)

typedef short short8 __attribute__((ext_vector_type(8)));
typedef float f32x4 __attribute__((ext_vector_type(4)));

union S8 {
  short8 v;
  unsigned short s[8];
};

__device__ __forceinline__ unsigned bf16rne(float x) {
  unsigned u = __float_as_uint(x);
  u += 0x7FFFu + ((u >> 16) & 1u);
  return u >> 16;
}

__device__ __forceinline__ void cvt_split8(const float4& f0, const float4& f1,
                                           short8& hv8, short8& lv8) {
  float xs[8] = {f0.x, f0.y, f0.z, f0.w, f1.x, f1.y, f1.z, f1.w};
  S8 hv, lv;
#pragma unroll
  for (int e = 0; e < 8; ++e) {
    unsigned u = __float_as_uint(xs[e]);
    unsigned hu = u & 0xFFFF0000u;  // truncated hi
    hv.s[e] = (unsigned short)(hu >> 16);
    float lo = xs[e] - __uint_as_float(hu);  // exact remainder
    unsigned ul = __float_as_uint(lo);
    ul += 0x7FFFu + ((ul >> 16) & 1u);  // RNE
    lv.s[e] = (unsigned short)(ul >> 16);
  }
  hv8 = hv.v;
  lv8 = lv.v;
}

// ---------------- Kernel A: split-bf16 MFMA GEMMs --------------------------
__global__ __launch_bounds__(512) void gemm_k(const float* __restrict__ Q,
                                              const float* __restrict__ Kin,
                                              const float* __restrict__ W1,
                                              const float* __restrict__ b1,
                                              float* __restrict__ hh,
                                              unsigned* __restrict__ kT2) {
  __shared__ short AH[64 * 32], AL[64 * 32], BH[64 * 32], BL[64 * 32];
  const int t = threadIdx.x;
  const int blk = blockIdx.x;
  const bool isK = blk >= 128;
  const float *A, *B;
  int lda, ldb, m0, n0, aoff;
  if (!isK) {
    int bm = blk >> 3, bn = blk & 7;
    m0 = bm * 64; n0 = bn * 64;
    A = Q;   lda = 256; aoff = 0;
    B = W1;  ldb = 512;              // cols 0..255 of W1 rows (h)
  } else {
    int t2 = blk - 128;
    int bm = t2 >> 4, bn = t2 & 15;
    m0 = bm * 64; n0 = bn * 64;
    A = W1;  lda = 512; aoff = 256;  // W1k rows = h
    B = Kin; ldb = 256;              // rows = bk
  }
  const int mat = t >> 8;            // 0 = A, 1 = B
  const int cc = t & 255;
  const int sr = cc >> 2;            // row in tile 0..63
  const int c8 = (cc & 3) * 8;       // k-chunk
  const float* srcbase =
      mat ? (B + (size_t)(n0 + sr) * ldb + c8)
          : (A + (size_t)(m0 + sr) * lda + aoff + c8);
  short* dstH = (mat ? BH : AH) + sr * 32 + c8;
  short* dstL = (mat ? BL : AL) + sr * 32 + c8;

  const int w = t >> 6, lane = t & 63;
  const int wr = (w >> 2) * 32, wc = (w & 3) * 16;
  const int lane15 = lane & 15, lk8 = (lane >> 4) * 8;

  f32x4 acc[2] = {{0.f, 0.f, 0.f, 0.f}, {0.f, 0.f, 0.f, 0.f}};

  float4 f0 = *(const float4*)&srcbase[0];
  float4 f1 = *(const float4*)&srcbase[4];
  for (int ks = 0; ks < 8; ++ks) {
    short8 hv8, lv8;
    cvt_split8(f0, f1, hv8, lv8);  // register-only
    __syncthreads();               // previous iteration's ds_reads done
    *(short8*)dstH = hv8;
    *(short8*)dstL = lv8;
    __syncthreads();
    if (ks < 7) {                  // next-tile loads hide under MFMAs
      f0 = *(const float4*)&srcbase[(ks + 1) * 32];
      f1 = *(const float4*)&srcbase[(ks + 1) * 32 + 4];
    }
    short8 ah0 = *(const short8*)&AH[(wr + lane15) * 32 + lk8];
    short8 ah1 = *(const short8*)&AH[(wr + 16 + lane15) * 32 + lk8];
    short8 al0 = *(const short8*)&AL[(wr + lane15) * 32 + lk8];
    short8 al1 = *(const short8*)&AL[(wr + 16 + lane15) * 32 + lk8];
    short8 bh = *(const short8*)&BH[(wc + lane15) * 32 + lk8];
    short8 bl = *(const short8*)&BL[(wc + lane15) * 32 + lk8];
    acc[0] = __builtin_amdgcn_mfma_f32_16x16x32_bf16(ah0, bh, acc[0], 0, 0, 0);
    acc[1] = __builtin_amdgcn_mfma_f32_16x16x32_bf16(ah1, bh, acc[1], 0, 0, 0);
    acc[0] = __builtin_amdgcn_mfma_f32_16x16x32_bf16(ah0, bl, acc[0], 0, 0, 0);
    acc[1] = __builtin_amdgcn_mfma_f32_16x16x32_bf16(ah1, bl, acc[1], 0, 0, 0);
    acc[0] = __builtin_amdgcn_mfma_f32_16x16x32_bf16(al0, bh, acc[0], 0, 0, 0);
    acc[1] = __builtin_amdgcn_mfma_f32_16x16x32_bf16(al1, bh, acc[1], 0, 0, 0);
  }
  const int lg4 = (lane >> 4) * 4;
  if (!isK) {
#pragma unroll
    for (int i = 0; i < 2; ++i) {
#pragma unroll
      for (int reg = 0; reg < 4; ++reg) {
        int row = m0 + wr + i * 16 + lg4 + reg;
        hh[(size_t)row * 512 + n0 + wc + lane15] = acc[i][reg];
      }
    }
  } else {
    const int col = n0 + wc + lane15;
#pragma unroll
    for (int i = 0; i < 2; ++i) {
      int r0 = m0 + wr + i * 16 + lg4;  // even, rows r0..r0+3
      float v0 = acc[i][0] + b1[r0 + 0];
      float v1 = acc[i][1] + b1[r0 + 1];
      float v2 = acc[i][2] + b1[r0 + 2];
      float v3 = acc[i][3] + b1[r0 + 3];
      unsigned p01 = bf16rne(v0) | (bf16rne(v1) << 16);
      unsigned p23 = bf16rne(v2) | (bf16rne(v3) << 16);
      int hp = r0 >> 1;
      kT2[(size_t)hp * 1024 + col] = p01;
      kT2[(size_t)(hp + 1) * 1024 + col] = p23;
    }
  }
}

// ---------------- Kernel B: compacted scores + softmax + PV ----------------
__global__ __launch_bounds__(512) void attn_k(const float* __restrict__ hh,
                                              const unsigned* __restrict__ kT2,
                                              const float* __restrict__ V,
                                              const void* __restrict__ maskp,
                                              const float* __restrict__ W2,
                                              float* __restrict__ out) {
  __shared__ float smem[14016];  // 56.06 KB
  __shared__ int sflag, nkS;
  __shared__ int wsumS[4];
  __shared__ int kidxS[256];
  float* att = smem;             // [4][260]
  float* rowsum = smem + 1040;   // [4]
  float* qlin = smem + 1044;     // [4]
  float* qs = smem + 1056;       // [4][512]
  float* w2s = smem + 3104;      // [512]
  float* sabs = smem + 3616;     // [8 w][4 q][260] (compact col index)
  float* klin = smem + 11936;    // [8 w][260]     (compact col index)
  float* red = smem + 3616;      // [8 w][4 q][264] overlays sabs in PV

  const int t = threadIdx.x;
  const int blk = blockIdx.x;
  const int b = blk >> 6;
  const int q4 = blk & 63;
  const int w = t >> 6, lane = t & 63;

  if (t == 0) sflag = 0;
  // stage q rows + W2
  {
    const float* qbase = hh + (size_t)(b * 256 + q4 * 4) * 512;
    int row = t >> 7, c4 = (t & 127) * 4;
    *(float4*)&qs[row * 512 + c4] = *(const float4*)&qbase[(size_t)row * 512 + c4];
    if (t < 128) *(float4*)&w2s[t * 4] = *(const float4*)&W2[t * 4];
  }
  __syncthreads();
  // mask dtype probe: nonzero high bytes in first 1KB => byte mask
  if (t < 256) {
    const unsigned char* mb = (const unsigned char*)maskp;
    int nz = mb[t * 4 + 1] | mb[t * 4 + 2] | mb[t * 4 + 3];
    if (nz) atomicOr(&sflag, 1);
  }
  // qlin for rows 0..3 (waves 0..3) — needs qs/w2s staged
  if (w < 4) {
    float p = 0.f;
#pragma unroll
    for (int u = 0; u < 8; ++u)
      p = fmaf(w2s[lane + 64 * u], qs[w * 512 + lane + 64 * u], p);
#pragma unroll
    for (int o = 32; o; o >>= 1) p += __shfl_xor(p, o, 64);
    if (lane == 0) qlin[w] = 0.505f * p;
  }
  __syncthreads();  // sflag final
  // compaction: active columns -> kidxS[0..nk)
  bool act = false;
  int pre = 0;
  if (t < 256) {
    const int flag = sflag;
    const unsigned char* m8 = (const unsigned char*)maskp;
    const int* m32 = (const int*)maskp;
    act = flag ? (m8[b * 256 + t] == 0) : (m32[b * 256 + t] == 0);
    unsigned long long bal = __ballot(act);
    pre = __popcll(bal & ((1ull << lane) - 1ull));
    if (lane == 0) wsumS[w] = __popcll(bal);
  }
  __syncthreads();  // wsumS ready
  if (t < 256 && act) {
    int off = 0;
#pragma unroll
    for (int ww = 0; ww < 4; ++ww)
      if (ww < w) off += wsumS[ww];
    kidxS[off + pre] = t;
  }
  if (t == 0) nkS = wsumS[0] + wsumS[1] + wsumS[2] + wsumS[3];
  __syncthreads();  // kidxS / nkS ready
  const int nk = nkS;
  const int ncg = (nk + 63) >> 6;

  // main loop: wave w covers h in [w*64,w*64+64); lane owns 1 compact col
  // per active column-group.
  {
    float sa[4][4] = {};  // [q][cg]
    float kl[4] = {};     // [cg]
    const unsigned* kTbase = kT2 + (size_t)b * 256;
    const unsigned* colp[4];
#pragma unroll
    for (int cg = 0; cg < 4; ++cg) {
      int ci = cg * 64 + lane;
      int kc = kidxS[ci < nk ? ci : (nk - 1)];
      colp[cg] = kTbase + kc;
    }
    const int hbase = w * 64;
#pragma unroll 2
    for (int hg = 0; hg < 16; ++hg) {
      const int h = hbase + hg * 4;
      const int hp = h >> 1;
      unsigned ua[4], ub[4];
#pragma unroll
      for (int cg = 0; cg < 4; ++cg)
        if (cg < ncg) {
          ua[cg] = colp[cg][(size_t)hp * 1024];
          ub[cg] = colp[cg][(size_t)(hp + 1) * 1024];
        }
      float w24[4], qv[4][4];
      *(float4*)w24 = *(const float4*)&w2s[h];
#pragma unroll
      for (int q = 0; q < 4; ++q)
        *(float4*)qv[q] = *(const float4*)&qs[q * 512 + h];
#pragma unroll
      for (int cg = 0; cg < 4; ++cg)
        if (cg < ncg) {
          float kv[4];
          kv[0] = __uint_as_float(ua[cg] << 16);
          kv[1] = __uint_as_float(ua[cg] & 0xFFFF0000u);
          kv[2] = __uint_as_float(ub[cg] << 16);
          kv[3] = __uint_as_float(ub[cg] & 0xFFFF0000u);
#pragma unroll
          for (int e = 0; e < 4; ++e) {
            kl[cg] = fmaf(w24[e], kv[e], kl[cg]);
#pragma unroll
            for (int q = 0; q < 4; ++q)
              sa[q][cg] = fmaf(w24[e], fabsf(qv[q][e] + kv[e]), sa[q][cg]);
          }
        }
    }
#pragma unroll
    for (int cg = 0; cg < 4; ++cg)
      if (cg < ncg) {
        int ci = cg * 64 + lane;
#pragma unroll
        for (int q = 0; q < 4; ++q) sabs[(w * 4 + q) * 260 + ci] = sa[q][cg];
        klin[w * 260 + ci] = kl[cg];
      }
  }
  __syncthreads();
  // init att to -1e9 (masked default)
  if (t < 256) {
#pragma unroll
    for (int q = 0; q < 4; ++q) att[q * 260 + t] = -1e9f;
  }
  __syncthreads();
  // scatter active scores: thread t < nk handles compact col t
  if (t < nk) {
    const int realk = kidxS[t];
    float kls = 0.f;
#pragma unroll
    for (int ww = 0; ww < 8; ++ww) kls += klin[ww * 260 + t];
    kls *= 0.505f;
#pragma unroll
    for (int q = 0; q < 4; ++q) {
      float v = 0.f;
#pragma unroll
      for (int ww = 0; ww < 8; ++ww) v += sabs[(ww * 4 + q) * 260 + t];
      att[q * 260 + realk] = qlin[q] + kls + 0.495f * v;
    }
  }
  __syncthreads();
  // softmax: wave w<4 -> row w
  if (w < 4) {
    float m = -1e30f;
#pragma unroll
    for (int u = 0; u < 4; ++u) m = fmaxf(m, att[w * 260 + lane + 64 * u]);
#pragma unroll
    for (int o = 32; o; o >>= 1) m = fmaxf(m, __shfl_xor(m, o, 64));
    float ssum = 0.f;
#pragma unroll
    for (int u = 0; u < 4; ++u) {
      float e = __expf(att[w * 260 + lane + 64 * u] - m);
      att[w * 260 + lane + 64 * u] = e;
      ssum += e;
    }
#pragma unroll
    for (int o = 32; o; o >>= 1) ssum += __shfl_xor(ssum, o, 64);
    if (lane == 0) rowsum[w] = ssum;
  }
  __syncthreads();
  // PV over compacted k: wave w takes i = w, w+8, ...; V rows coalesced
  {
    const int v0 = lane * 4;
    const float* Vb = V + (size_t)b * 65536;
    float acc[4][4] = {};
    for (int i = w; i < nk; i += 8) {
      int k = kidxS[i];
      float4 vv = *(const float4*)&Vb[(size_t)k * 256 + v0];
      float aw[4];
#pragma unroll
      for (int q = 0; q < 4; ++q) aw[q] = att[q * 260 + k];
#pragma unroll
      for (int q = 0; q < 4; ++q) {
        acc[q][0] = fmaf(aw[q], vv.x, acc[q][0]);
        acc[q][1] = fmaf(aw[q], vv.y, acc[q][1]);
        acc[q][2] = fmaf(aw[q], vv.z, acc[q][2]);
        acc[q][3] = fmaf(aw[q], vv.w, acc[q][3]);
      }
    }
#pragma unroll
    for (int q = 0; q < 4; ++q)
      *(float4*)&red[(w * 4 + q) * 264 + v0] =
          make_float4(acc[q][0], acc[q][1], acc[q][2], acc[q][3]);
  }
  __syncthreads();
  // final reduce over 8 wave-partials + normalize
#pragma unroll
  for (int s = 0; s < 2; ++s) {
    int id = t + s * 512;
    int row = id >> 8, col = id & 255;
    float v = 0.f;
#pragma unroll
    for (int g = 0; g < 8; ++g) v += red[(g * 4 + row) * 264 + col];
    out[((size_t)b * 256 + q4 * 4 + row) * 256 + col] = v / rowsum[row];
  }
}

extern "C" void kernel_launch(void* const* d_in, const int* in_sizes, int n_in,
                              void* d_out, int out_size, void* d_ws,
                              size_t ws_size, hipStream_t stream) {
  const float* Q = (const float*)d_in[0];
  const float* K = (const float*)d_in[1];
  const float* V = (const float*)d_in[2];
  const void* mask = d_in[3];
  const float* W1 = (const float*)d_in[4];
  const float* b1 = (const float*)d_in[5];
  const float* W2 = (const float*)d_in[6];
  float* ws = (float*)d_ws;
  float* hh = ws + HH_OFF;
  unsigned* kT2 = (unsigned*)(ws + KT_OFF);
  float* out = (float*)d_out;

  gemm_k<<<dim3(256), dim3(512), 0, stream>>>(Q, K, W1, b1, hh, kT2);
  attn_k<<<dim3(256), dim3(512), 0, stream>>>(hh, kT2, V, mask, W2, out);
}

// Round 9
// 30.285 us; speedup vs baseline: 1.1477x; 1.1477x over previous
//
#include <hip/hip_runtime.h>

// ConcatAttention: B=4, SQ=SK=256, DQ=DK=DV=256, D=512
// score[b,q,k] = sum_h W2[h]*leaky(q_h+k_h+b1),  leaky(x)=0.505x+0.495|x|
//   => score = qlin[q] + klin[k] + 0.495*sum_h W2[h]*|q_h + (k_h+b1)|
//
// Kernel A (256 blk x 512 thr): split-bf16 MFMA GEMMs (A*B^T, row-major).
//   blk<128 : hh[q][h] = Q @ W1[:, :256]^T            (fp32 out)
//   blk>=128: kT2[hp][b*256+j] = packed-bf16 (W1k @ K^T + b1) with COLUMNS
//             COMPACTED to the batch's active (unmasked) k, via in-block
//             mask scan + row gather in LDS staging. Padded cols dup last.
// Kernel B (256 blk x 512 thr): block=(b, 4 q-rows). Wave w covers h range
//   [w*64,w*64+64) split over 4 gangs of 16 lanes (16 h each); lane owns 4
//   CONTIGUOUS compacted cols (coalesced uint4). Trip count = 4*ceil(nk/64).
//   Cross-gang reduce via shfl_xor(16,32). PV over compacted k.
//
// ws: hh [1024][512] f32, kT2 [256][1024] u32
#define HH_OFF 0
#define KT_OFF (1024 * 512)

typedef short short8 __attribute__((ext_vector_type(8)));
typedef float f32x4 __attribute__((ext_vector_type(4)));

union S8 {
  short8 v;
  unsigned short s[8];
};

__device__ __forceinline__ unsigned bf16rne(float x) {
  unsigned u = __float_as_uint(x);
  u += 0x7FFFu + ((u >> 16) & 1u);
  return u >> 16;
}

__device__ __forceinline__ void cvt_split8(const float4& f0, const float4& f1,
                                           short8& hv8, short8& lv8) {
  float xs[8] = {f0.x, f0.y, f0.z, f0.w, f1.x, f1.y, f1.z, f1.w};
  S8 hv, lv;
#pragma unroll
  for (int e = 0; e < 8; ++e) {
    unsigned u = __float_as_uint(xs[e]);
    unsigned hu = u & 0xFFFF0000u;  // truncated hi
    hv.s[e] = (unsigned short)(hu >> 16);
    float lo = xs[e] - __uint_as_float(hu);  // exact remainder
    unsigned ul = __float_as_uint(lo);
    ul += 0x7FFFu + ((ul >> 16) & 1u);  // RNE
    lv.s[e] = (unsigned short)(ul >> 16);
  }
  hv8 = hv.v;
  lv8 = lv.v;
}

// ---------------- Kernel A: split-bf16 MFMA GEMMs --------------------------
__global__ __launch_bounds__(512) void gemm_k(const float* __restrict__ Q,
                                              const float* __restrict__ Kin,
                                              const float* __restrict__ W1,
                                              const float* __restrict__ b1,
                                              const void* __restrict__ maskp,
                                              float* __restrict__ hh,
                                              unsigned* __restrict__ kT2) {
  __shared__ short AH[64 * 32], AL[64 * 32], BH[64 * 32], BL[64 * 32];
  __shared__ int sflag, nkS, wsumS[4], kidxS[256];
  const int t = threadIdx.x;
  const int blk = blockIdx.x;
  const bool isK = blk >= 128;
  const float *A, *B;
  int lda, ldb, m0, n0, aoff, bb = 0, cchunk = 0;
  if (!isK) {
    int bm = blk >> 3, bn = blk & 7;
    m0 = bm * 64; n0 = bn * 64;
    A = Q;   lda = 256; aoff = 0;
    B = W1;  ldb = 512;              // cols 0..255 of W1 rows (h)
  } else {
    int t2 = blk - 128;
    int bm = t2 >> 4, bn = t2 & 15;
    m0 = bm * 64; n0 = bn * 64;      // n0 = bb*256 + cchunk*64
    A = W1;  lda = 512; aoff = 256;  // W1k rows = h
    B = Kin; ldb = 256;
    bb = bn >> 2; cchunk = bn & 3;
    // ---- mask scan for batch bb: kidxS[0..nk), nkS ----
    if (t == 0) sflag = 0;
    __syncthreads();
    if (t < 256) {
      const unsigned char* mb = (const unsigned char*)maskp;
      int nz = mb[t * 4 + 1] | mb[t * 4 + 2] | mb[t * 4 + 3];
      if (nz) atomicOr(&sflag, 1);
    }
    __syncthreads();
    const int w_ = t >> 6, lane_ = t & 63;
    bool act = false;
    int pre = 0;
    if (t < 256) {
      const int flag = sflag;
      const unsigned char* m8 = (const unsigned char*)maskp;
      const int* m32 = (const int*)maskp;
      act = flag ? (m8[bb * 256 + t] == 0) : (m32[bb * 256 + t] == 0);
      unsigned long long bal = __ballot(act);
      pre = __popcll(bal & ((1ull << lane_) - 1ull));
      if (lane_ == 0) wsumS[w_] = __popcll(bal);
    }
    __syncthreads();
    if (t < 256 && act) {
      int off = 0;
#pragma unroll
      for (int ww = 0; ww < 4; ++ww)
        if (ww < w_) off += wsumS[ww];
      kidxS[off + pre] = t;
    }
    if (t == 0) nkS = wsumS[0] + wsumS[1] + wsumS[2] + wsumS[3];
    __syncthreads();
    if (cchunk * 64 >= ((nkS + 63) & ~63)) return;  // inactive chunk (uniform)
  }
  // staging: thread t -> one 8-elem chunk of A or B tile
  const int mat = t >> 8;            // 0 = A, 1 = B
  const int cc = t & 255;
  const int sr = cc >> 2;            // row in tile 0..63
  const int c8 = (cc & 3) * 8;       // k-chunk
  const float* srcbase;
  if (mat == 0) {
    srcbase = A + (size_t)(m0 + sr) * lda + aoff + c8;
  } else if (!isK) {
    srcbase = B + (size_t)(n0 + sr) * ldb + c8;
  } else {
    int jl = cchunk * 64 + sr;                     // compact col in batch
    int kr = kidxS[jl < nkS ? jl : nkS - 1];       // gather (clamped dup)
    srcbase = Kin + (size_t)(bb * 256 + kr) * 256 + c8;
  }
  short* dstH = (mat ? BH : AH) + sr * 32 + c8;
  short* dstL = (mat ? BL : AL) + sr * 32 + c8;

  const int w = t >> 6, lane = t & 63;
  const int wr = (w >> 2) * 32, wc = (w & 3) * 16;
  const int lane15 = lane & 15, lk8 = (lane >> 4) * 8;

  f32x4 acc[2] = {{0.f, 0.f, 0.f, 0.f}, {0.f, 0.f, 0.f, 0.f}};

  float4 f0 = *(const float4*)&srcbase[0];
  float4 f1 = *(const float4*)&srcbase[4];
  for (int ks = 0; ks < 8; ++ks) {
    short8 hv8, lv8;
    cvt_split8(f0, f1, hv8, lv8);  // register-only
    __syncthreads();               // previous iteration's ds_reads done
    *(short8*)dstH = hv8;
    *(short8*)dstL = lv8;
    __syncthreads();
    if (ks < 7) {                  // next-tile loads hide under MFMAs
      f0 = *(const float4*)&srcbase[(ks + 1) * 32];
      f1 = *(const float4*)&srcbase[(ks + 1) * 32 + 4];
    }
    short8 ah0 = *(const short8*)&AH[(wr + lane15) * 32 + lk8];
    short8 ah1 = *(const short8*)&AH[(wr + 16 + lane15) * 32 + lk8];
    short8 al0 = *(const short8*)&AL[(wr + lane15) * 32 + lk8];
    short8 al1 = *(const short8*)&AL[(wr + 16 + lane15) * 32 + lk8];
    short8 bh = *(const short8*)&BH[(wc + lane15) * 32 + lk8];
    short8 bl = *(const short8*)&BL[(wc + lane15) * 32 + lk8];
    acc[0] = __builtin_amdgcn_mfma_f32_16x16x32_bf16(ah0, bh, acc[0], 0, 0, 0);
    acc[1] = __builtin_amdgcn_mfma_f32_16x16x32_bf16(ah1, bh, acc[1], 0, 0, 0);
    acc[0] = __builtin_amdgcn_mfma_f32_16x16x32_bf16(ah0, bl, acc[0], 0, 0, 0);
    acc[1] = __builtin_amdgcn_mfma_f32_16x16x32_bf16(ah1, bl, acc[1], 0, 0, 0);
    acc[0] = __builtin_amdgcn_mfma_f32_16x16x32_bf16(al0, bh, acc[0], 0, 0, 0);
    acc[1] = __builtin_amdgcn_mfma_f32_16x16x32_bf16(al1, bh, acc[1], 0, 0, 0);
  }
  const int lg4 = (lane >> 4) * 4;
  if (!isK) {
#pragma unroll
    for (int i = 0; i < 2; ++i) {
#pragma unroll
      for (int reg = 0; reg < 4; ++reg) {
        int row = m0 + wr + i * 16 + lg4 + reg;
        hh[(size_t)row * 512 + n0 + wc + lane15] = acc[i][reg];
      }
    }
  } else {
    const int col = n0 + wc + lane15;  // compacted column
#pragma unroll
    for (int i = 0; i < 2; ++i) {
      int r0 = m0 + wr + i * 16 + lg4;  // even, rows r0..r0+3
      float v0 = acc[i][0] + b1[r0 + 0];
      float v1 = acc[i][1] + b1[r0 + 1];
      float v2 = acc[i][2] + b1[r0 + 2];
      float v3 = acc[i][3] + b1[r0 + 3];
      unsigned p01 = bf16rne(v0) | (bf16rne(v1) << 16);
      unsigned p23 = bf16rne(v2) | (bf16rne(v3) << 16);
      int hp = r0 >> 1;
      kT2[(size_t)hp * 1024 + col] = p01;
      kT2[(size_t)(hp + 1) * 1024 + col] = p23;
    }
  }
}

// ---------------- Kernel B: compacted scores + softmax + PV ----------------
__global__ __launch_bounds__(512) void attn_k(const float* __restrict__ hh,
                                              const unsigned* __restrict__ kT2,
                                              const float* __restrict__ V,
                                              const void* __restrict__ maskp,
                                              const float* __restrict__ W2,
                                              float* __restrict__ out) {
  __shared__ float smem[14016];  // 56.06 KB
  __shared__ int sflag, nkS, wsumS[4];
  __shared__ int kidxS[256];
  float* att = smem;             // [4][260]
  float* rowsum = smem + 1040;   // [4]
  float* qlin = smem + 1044;     // [4]
  float* qs = smem + 1056;       // [4][512]
  float* w2s = smem + 3104;      // [512]
  float* sabs = smem + 3616;     // [8 w][4 q][260] (compact col index)
  float* klin = smem + 11936;    // [8 w][260]     (compact col index)
  float* red = smem + 3616;      // [8 w][4 q][264] overlays sabs in PV

  const int t = threadIdx.x;
  const int blk = blockIdx.x;
  const int b = blk >> 6;
  const int q4 = blk & 63;
  const int w = t >> 6, lane = t & 63;

  if (t == 0) sflag = 0;
  // stage q rows + W2
  {
    const float* qbase = hh + (size_t)(b * 256 + q4 * 4) * 512;
    int row = t >> 7, c4 = (t & 127) * 4;
    *(float4*)&qs[row * 512 + c4] = *(const float4*)&qbase[(size_t)row * 512 + c4];
    if (t < 128) *(float4*)&w2s[t * 4] = *(const float4*)&W2[t * 4];
  }
  __syncthreads();
  // mask dtype probe: nonzero high bytes in first 1KB => byte mask
  if (t < 256) {
    const unsigned char* mb = (const unsigned char*)maskp;
    int nz = mb[t * 4 + 1] | mb[t * 4 + 2] | mb[t * 4 + 3];
    if (nz) atomicOr(&sflag, 1);
  }
  // qlin for rows 0..3 (waves 0..3)
  if (w < 4) {
    float p = 0.f;
#pragma unroll
    for (int u = 0; u < 8; ++u)
      p = fmaf(w2s[lane + 64 * u], qs[w * 512 + lane + 64 * u], p);
#pragma unroll
    for (int o = 32; o; o >>= 1) p += __shfl_xor(p, o, 64);
    if (lane == 0) qlin[w] = 0.505f * p;
  }
  __syncthreads();  // sflag final
  // compaction indices (must match gemm_k's scan exactly)
  bool act = false;
  int pre = 0;
  if (t < 256) {
    const int flag = sflag;
    const unsigned char* m8 = (const unsigned char*)maskp;
    const int* m32 = (const int*)maskp;
    act = flag ? (m8[b * 256 + t] == 0) : (m32[b * 256 + t] == 0);
    unsigned long long bal = __ballot(act);
    pre = __popcll(bal & ((1ull << lane) - 1ull));
    if (lane == 0) wsumS[w] = __popcll(bal);
  }
  __syncthreads();
  if (t < 256 && act) {
    int off = 0;
#pragma unroll
    for (int ww = 0; ww < 4; ++ww)
      if (ww < w) off += wsumS[ww];
    kidxS[off + pre] = t;
  }
  if (t == 0) nkS = wsumS[0] + wsumS[1] + wsumS[2] + wsumS[3];
  __syncthreads();
  const int nk = nkS;
  const int nc64 = (nk + 63) >> 6;

  // main loop: wave w -> h in [w*64,+64), gang (lane>>4) -> 16-h slice;
  // lane owns 4 contiguous compacted cols per col-block (coalesced uint4).
  {
    const int gang = lane >> 4, li = lane & 15;
    const int hbase = w * 64 + gang * 16;
    const unsigned* kTb = kT2 + (size_t)b * 256;
#pragma unroll 1
    for (int cb = 0; cb < nc64; ++cb) {
      const int colo = cb * 64 + li * 4;
      float sa[4][4] = {};  // [q][c]
      float kl4[4] = {};
#pragma unroll
      for (int hg = 0; hg < 4; ++hg) {
        const int h = hbase + hg * 4;
        const int hp = h >> 1;
        uint4 ua = *(const uint4*)&kTb[(size_t)hp * 1024 + colo];
        uint4 ub = *(const uint4*)&kTb[(size_t)(hp + 1) * 1024 + colo];
        float w24[4], qv[4][4];
        *(float4*)w24 = *(const float4*)&w2s[h];
#pragma unroll
        for (int q = 0; q < 4; ++q)
          *(float4*)qv[q] = *(const float4*)&qs[q * 512 + h];
        unsigned uac[4] = {ua.x, ua.y, ua.z, ua.w};
        unsigned ubc[4] = {ub.x, ub.y, ub.z, ub.w};
        float kv[4][4];
#pragma unroll
        for (int c = 0; c < 4; ++c) {
          kv[0][c] = __uint_as_float(uac[c] << 16);
          kv[1][c] = __uint_as_float(uac[c] & 0xFFFF0000u);
          kv[2][c] = __uint_as_float(ubc[c] << 16);
          kv[3][c] = __uint_as_float(ubc[c] & 0xFFFF0000u);
        }
#pragma unroll
        for (int e = 0; e < 4; ++e) {
#pragma unroll
          for (int c = 0; c < 4; ++c) {
            kl4[c] = fmaf(w24[e], kv[e][c], kl4[c]);
#pragma unroll
            for (int q = 0; q < 4; ++q)
              sa[q][c] = fmaf(w24[e], fabsf(qv[q][e] + kv[e][c]), sa[q][c]);
          }
        }
      }
      // cross-gang butterfly (lanes ^16, ^32): totals over the wave's 64 h
#pragma unroll
      for (int q = 0; q < 4; ++q)
#pragma unroll
        for (int c = 0; c < 4; ++c) {
          sa[q][c] += __shfl_xor(sa[q][c], 16, 64);
          sa[q][c] += __shfl_xor(sa[q][c], 32, 64);
        }
#pragma unroll
      for (int c = 0; c < 4; ++c) {
        kl4[c] += __shfl_xor(kl4[c], 16, 64);
        kl4[c] += __shfl_xor(kl4[c], 32, 64);
      }
      if (gang == 0) {
#pragma unroll
        for (int q = 0; q < 4; ++q)
          *(float4*)&sabs[(w * 4 + q) * 260 + colo] =
              make_float4(sa[q][0], sa[q][1], sa[q][2], sa[q][3]);
        *(float4*)&klin[w * 260 + colo] =
            make_float4(kl4[0], kl4[1], kl4[2], kl4[3]);
      }
    }
  }
  __syncthreads();
  // init att to -1e9 (masked default)
  if (t < 256) {
#pragma unroll
    for (int q = 0; q < 4; ++q) att[q * 260 + t] = -1e9f;
  }
  __syncthreads();
  // scatter active scores: thread t < nk handles compact col t
  if (t < nk) {
    const int realk = kidxS[t];
    float kls = 0.f;
#pragma unroll
    for (int ww = 0; ww < 8; ++ww) kls += klin[ww * 260 + t];
    kls *= 0.505f;
#pragma unroll
    for (int q = 0; q < 4; ++q) {
      float v = 0.f;
#pragma unroll
      for (int ww = 0; ww < 8; ++ww) v += sabs[(ww * 4 + q) * 260 + t];
      att[q * 260 + realk] = qlin[q] + kls + 0.495f * v;
    }
  }
  __syncthreads();
  // softmax: wave w<4 -> row w
  if (w < 4) {
    float m = -1e30f;
#pragma unroll
    for (int u = 0; u < 4; ++u) m = fmaxf(m, att[w * 260 + lane + 64 * u]);
#pragma unroll
    for (int o = 32; o; o >>= 1) m = fmaxf(m, __shfl_xor(m, o, 64));
    float ssum = 0.f;
#pragma unroll
    for (int u = 0; u < 4; ++u) {
      float e = __expf(att[w * 260 + lane + 64 * u] - m);
      att[w * 260 + lane + 64 * u] = e;
      ssum += e;
    }
#pragma unroll
    for (int o = 32; o; o >>= 1) ssum += __shfl_xor(ssum, o, 64);
    if (lane == 0) rowsum[w] = ssum;
  }
  __syncthreads();
  // PV over compacted k: wave w takes i = w, w+8, ...; V rows coalesced
  {
    const int v0 = lane * 4;
    const float* Vb = V + (size_t)b * 65536;
    float acc[4][4] = {};
    for (int i = w; i < nk; i += 8) {
      int k = kidxS[i];
      float4 vv = *(const float4*)&Vb[(size_t)k * 256 + v0];
      float aw[4];
#pragma unroll
      for (int q = 0; q < 4; ++q) aw[q] = att[q * 260 + k];
#pragma unroll
      for (int q = 0; q < 4; ++q) {
        acc[q][0] = fmaf(aw[q], vv.x, acc[q][0]);
        acc[q][1] = fmaf(aw[q], vv.y, acc[q][1]);
        acc[q][2] = fmaf(aw[q], vv.z, acc[q][2]);
        acc[q][3] = fmaf(aw[q], vv.w, acc[q][3]);
      }
    }
#pragma unroll
    for (int q = 0; q < 4; ++q)
      *(float4*)&red[(w * 4 + q) * 264 + v0] =
          make_float4(acc[q][0], acc[q][1], acc[q][2], acc[q][3]);
  }
  __syncthreads();
  // final reduce over 8 wave-partials + normalize
#pragma unroll
  for (int s = 0; s < 2; ++s) {
    int id = t + s * 512;
    int row = id >> 8, col = id & 255;
    float v = 0.f;
#pragma unroll
    for (int g = 0; g < 8; ++g) v += red[(g * 4 + row) * 264 + col];
    out[((size_t)b * 256 + q4 * 4 + row) * 256 + col] = v / rowsum[row];
  }
}

extern "C" void kernel_launch(void* const* d_in, const int* in_sizes, int n_in,
                              void* d_out, int out_size, void* d_ws,
                              size_t ws_size, hipStream_t stream) {
  const float* Q = (const float*)d_in[0];
  const float* K = (const float*)d_in[1];
  const float* V = (const float*)d_in[2];
  const void* mask = d_in[3];
  const float* W1 = (const float*)d_in[4];
  const float* b1 = (const float*)d_in[5];
  const float* W2 = (const float*)d_in[6];
  float* ws = (float*)d_ws;
  float* hh = ws + HH_OFF;
  unsigned* kT2 = (unsigned*)(ws + KT_OFF);
  float* out = (float*)d_out;

  gemm_k<<<dim3(256), dim3(512), 0, stream>>>(Q, K, W1, b1, mask, hh, kT2);
  attn_k<<<dim3(256), dim3(512), 0, stream>>>(hh, kT2, V, mask, W2, out);
}

// Round 11
// 28.989 us; speedup vs baseline: 1.1991x; 1.0447x over previous
//
#include <hip/hip_runtime.h>

// ConcatAttention: B=4, SQ=SK=256, DQ=DK=DV=256, D=512
// score[b,q,k] = sum_h W2[h]*leaky(q_h+k_h+b1),  leaky(x)=0.505x+0.495|x|
//   => score = qlin[q] + klin[k] + 0.495*sum_h W2[h]*|q_h + (k_h+b1)|
//
// Kernel A (256 blk x 512 thr): split-bf16 MFMA GEMMs (A*B^T, row-major).
//   blk<128 : hh[q][h] = Q @ W1[:, :256]^T            (fp32 out)
//   blk>=128: kT2[hp][b*256+j] = packed-FP16 (W1k @ K^T + b1), columns
//             compacted to the batch's active k (in-block mask scan + row
//             gather in staging). Padded cols dup last active.
// Kernel B (256 blk x 512 thr): block=(b, 4 q-rows). Wave w covers h range
//   [w*64,+64) split over 4 gangs of 16 lanes; lane owns 4 contiguous
//   compacted cols (uint4). Score inner loop in packed fp16:
//   v_pk_add_f16 + sign-mask abs + v_dot2_f32_f16 (fp32 accum).
//   Cross-gang reduce shfl_xor(16,32); softmax; PV over compacted k.
//
// ws: hh [1024][512] f32, kT2 [256][1024] u32(half2)
#define HH_OFF 0
#define KT_OFF (1024 * 512)

typedef short short8 __attribute__((ext_vector_type(8)));
typedef float f32x4 __attribute__((ext_vector_type(4)));
typedef __fp16 half2v __attribute__((ext_vector_type(2)));

union S8 {
  short8 v;
  unsigned short s[8];
};
union H2U {
  half2v h;
  unsigned u;
};

__device__ __forceinline__ unsigned pkrtz(float a, float b) {
  H2U r;
  r.h = __builtin_amdgcn_cvt_pkrtz(a, b);
  return r.u;
}
__device__ __forceinline__ half2v uh(unsigned u) {
  H2U r;
  r.u = u;
  return r.h;
}
__device__ __forceinline__ float fdot2f(half2v a, half2v b, float c) {
#if __has_builtin(__builtin_amdgcn_fdot2)
  return __builtin_amdgcn_fdot2(a, b, c, false);
#else
  return c + (float)a.x * (float)b.x + (float)a.y * (float)b.y;
#endif
}
__device__ __forceinline__ half2v habs2(half2v a) {
  H2U r;
  r.h = a;
  r.u &= 0x7FFF7FFFu;
  return r.h;
}

__device__ __forceinline__ void cvt_split8(const float4& f0, const float4& f1,
                                           short8& hv8, short8& lv8) {
  float xs[8] = {f0.x, f0.y, f0.z, f0.w, f1.x, f1.y, f1.z, f1.w};
  S8 hv, lv;
#pragma unroll
  for (int e = 0; e < 8; ++e) {
    unsigned u = __float_as_uint(xs[e]);
    unsigned hu = u & 0xFFFF0000u;  // truncated hi
    hv.s[e] = (unsigned short)(hu >> 16);
    float lo = xs[e] - __uint_as_float(hu);  // exact remainder
    unsigned ul = __float_as_uint(lo);
    ul += 0x7FFFu + ((ul >> 16) & 1u);  // RNE
    lv.s[e] = (unsigned short)(ul >> 16);
  }
  hv8 = hv.v;
  lv8 = lv.v;
}

// ---------------- Kernel A: split-bf16 MFMA GEMMs --------------------------
__global__ __launch_bounds__(512) void gemm_k(const float* __restrict__ Q,
                                              const float* __restrict__ Kin,
                                              const float* __restrict__ W1,
                                              const float* __restrict__ b1,
                                              const void* __restrict__ maskp,
                                              float* __restrict__ hh,
                                              unsigned* __restrict__ kT2) {
  __shared__ short AH[64 * 32], AL[64 * 32], BH[64 * 32], BL[64 * 32];
  __shared__ int sflag, nkS, wsumS[4], kidxS[256];
  const int t = threadIdx.x;
  const int blk = blockIdx.x;
  const bool isK = blk >= 128;
  const float *A, *B;
  int lda, ldb, m0, n0, aoff, bb = 0, cchunk = 0;
  if (!isK) {
    int bm = blk >> 3, bn = blk & 7;
    m0 = bm * 64; n0 = bn * 64;
    A = Q;   lda = 256; aoff = 0;
    B = W1;  ldb = 512;
  } else {
    int t2 = blk - 128;
    int bm = t2 >> 4, bn = t2 & 15;
    m0 = bm * 64; n0 = bn * 64;
    A = W1;  lda = 512; aoff = 256;
    B = Kin; ldb = 256;
    bb = bn >> 2; cchunk = bn & 3;
    // mask scan for batch bb
    if (t == 0) sflag = 0;
    __syncthreads();
    if (t < 256) {
      const unsigned char* mb = (const unsigned char*)maskp;
      int nz = mb[t * 4 + 1] | mb[t * 4 + 2] | mb[t * 4 + 3];
      if (nz) atomicOr(&sflag, 1);
    }
    __syncthreads();
    const int w_ = t >> 6, lane_ = t & 63;
    bool act = false;
    int pre = 0;
    if (t < 256) {
      const int flag = sflag;
      const unsigned char* m8 = (const unsigned char*)maskp;
      const int* m32 = (const int*)maskp;
      act = flag ? (m8[bb * 256 + t] == 0) : (m32[bb * 256 + t] == 0);
      unsigned long long bal = __ballot(act);
      pre = __popcll(bal & ((1ull << lane_) - 1ull));
      if (lane_ == 0) wsumS[w_] = __popcll(bal);
    }
    __syncthreads();
    if (t < 256 && act) {
      int off = 0;
#pragma unroll
      for (int ww = 0; ww < 4; ++ww)
        if (ww < w_) off += wsumS[ww];
      kidxS[off + pre] = t;
    }
    if (t == 0) nkS = wsumS[0] + wsumS[1] + wsumS[2] + wsumS[3];
    __syncthreads();
    if (cchunk * 64 >= ((nkS + 63) & ~63)) return;  // inactive chunk
  }
  const int mat = t >> 8;
  const int cc = t & 255;
  const int sr = cc >> 2;
  const int c8 = (cc & 3) * 8;
  const float* srcbase;
  if (mat == 0) {
    srcbase = A + (size_t)(m0 + sr) * lda + aoff + c8;
  } else if (!isK) {
    srcbase = B + (size_t)(n0 + sr) * ldb + c8;
  } else {
    int jl = cchunk * 64 + sr;
    int kr = kidxS[jl < nkS ? jl : nkS - 1];
    srcbase = Kin + (size_t)(bb * 256 + kr) * 256 + c8;
  }
  short* dstH = (mat ? BH : AH) + sr * 32 + c8;
  short* dstL = (mat ? BL : AL) + sr * 32 + c8;

  const int w = t >> 6, lane = t & 63;
  const int wr = (w >> 2) * 32, wc = (w & 3) * 16;
  const int lane15 = lane & 15, lk8 = (lane >> 4) * 8;

  f32x4 acc[2] = {{0.f, 0.f, 0.f, 0.f}, {0.f, 0.f, 0.f, 0.f}};

  float4 f0 = *(const float4*)&srcbase[0];
  float4 f1 = *(const float4*)&srcbase[4];
  for (int ks = 0; ks < 8; ++ks) {
    short8 hv8, lv8;
    cvt_split8(f0, f1, hv8, lv8);
    __syncthreads();
    *(short8*)dstH = hv8;
    *(short8*)dstL = lv8;
    __syncthreads();
    if (ks < 7) {
      f0 = *(const float4*)&srcbase[(ks + 1) * 32];
      f1 = *(const float4*)&srcbase[(ks + 1) * 32 + 4];
    }
    short8 ah0 = *(const short8*)&AH[(wr + lane15) * 32 + lk8];
    short8 ah1 = *(const short8*)&AH[(wr + 16 + lane15) * 32 + lk8];
    short8 al0 = *(const short8*)&AL[(wr + lane15) * 32 + lk8];
    short8 al1 = *(const short8*)&AL[(wr + 16 + lane15) * 32 + lk8];
    short8 bh = *(const short8*)&BH[(wc + lane15) * 32 + lk8];
    short8 bl = *(const short8*)&BL[(wc + lane15) * 32 + lk8];
    acc[0] = __builtin_amdgcn_mfma_f32_16x16x32_bf16(ah0, bh, acc[0], 0, 0, 0);
    acc[1] = __builtin_amdgcn_mfma_f32_16x16x32_bf16(ah1, bh, acc[1], 0, 0, 0);
    acc[0] = __builtin_amdgcn_mfma_f32_16x16x32_bf16(ah0, bl, acc[0], 0, 0, 0);
    acc[1] = __builtin_amdgcn_mfma_f32_16x16x32_bf16(ah1, bl, acc[1], 0, 0, 0);
    acc[0] = __builtin_amdgcn_mfma_f32_16x16x32_bf16(al0, bh, acc[0], 0, 0, 0);
    acc[1] = __builtin_amdgcn_mfma_f32_16x16x32_bf16(al1, bh, acc[1], 0, 0, 0);
  }
  const int lg4 = (lane >> 4) * 4;
  if (!isK) {
#pragma unroll
    for (int i = 0; i < 2; ++i) {
#pragma unroll
      for (int reg = 0; reg < 4; ++reg) {
        int row = m0 + wr + i * 16 + lg4 + reg;
        hh[(size_t)row * 512 + n0 + wc + lane15] = acc[i][reg];
      }
    }
  } else {
    const int col = n0 + wc + lane15;  // compacted column
#pragma unroll
    for (int i = 0; i < 2; ++i) {
      int r0 = m0 + wr + i * 16 + lg4;  // even
      float v0 = acc[i][0] + b1[r0 + 0];
      float v1 = acc[i][1] + b1[r0 + 1];
      float v2 = acc[i][2] + b1[r0 + 2];
      float v3 = acc[i][3] + b1[r0 + 3];
      int hp = r0 >> 1;
      kT2[(size_t)hp * 1024 + col] = pkrtz(v0, v1);
      kT2[(size_t)(hp + 1) * 1024 + col] = pkrtz(v2, v3);
    }
  }
}

// ---------------- Kernel B: fp16-packed scores + softmax + PV --------------
__global__ __launch_bounds__(512) void attn_k(const float* __restrict__ hh,
                                              const unsigned* __restrict__ kT2,
                                              const float* __restrict__ V,
                                              const void* __restrict__ maskp,
                                              const float* __restrict__ W2,
                                              float* __restrict__ out) {
  __shared__ float smem[15296];  // 61.2 KB
  __shared__ int sflag, nkS, wsumS[4];
  __shared__ int kidxS[256];
  float* att = smem;                            // [4][260]
  float* rowsum = smem + 1040;                  // [4]
  float* qlin = smem + 1044;                    // [4]
  float* qs = smem + 1048;                      // [4][512] f32
  float* w2s = smem + 3096;                     // [512] f32
  unsigned* w2p = (unsigned*)(smem + 3608);     // [256] half2
  unsigned* qp = (unsigned*)(smem + 3864);      // [4][256] half2
  float* sabs = smem + 4888;                    // [8][4][260]
  float* klin = smem + 13208;                   // [8][260]
  float* red = smem + 4888;                     // [8][4][264] overlays sabs

  const int t = threadIdx.x;
  const int blk = blockIdx.x;
  const int b = blk >> 6;
  const int q4 = blk & 63;
  const int w = t >> 6, lane = t & 63;

  if (t == 0) sflag = 0;
  // stage q rows (fp32) + W2
  {
    const float* qbase = hh + (size_t)(b * 256 + q4 * 4) * 512;
    int row = t >> 7, c4 = (t & 127) * 4;
    *(float4*)&qs[row * 512 + c4] = *(const float4*)&qbase[(size_t)row * 512 + c4];
    if (t < 128) *(float4*)&w2s[t * 4] = *(const float4*)&W2[t * 4];
  }
  __syncthreads();
  // packed fp16 copies: w2p, qp
  if (t < 256) {
    w2p[t] = pkrtz(w2s[2 * t], w2s[2 * t + 1]);
  }
  {
    int row = t >> 7, p0 = (t & 127) * 2;  // 2 pairs per thread
    qp[row * 256 + p0] = pkrtz(qs[row * 512 + 2 * p0], qs[row * 512 + 2 * p0 + 1]);
    qp[row * 256 + p0 + 1] =
        pkrtz(qs[row * 512 + 2 * p0 + 2], qs[row * 512 + 2 * p0 + 3]);
  }
  // mask dtype probe
  if (t < 256) {
    const unsigned char* mb = (const unsigned char*)maskp;
    int nz = mb[t * 4 + 1] | mb[t * 4 + 2] | mb[t * 4 + 3];
    if (nz) atomicOr(&sflag, 1);
  }
  // qlin rows 0..3 (fp32 precision)
  if (w < 4) {
    float p = 0.f;
#pragma unroll
    for (int u = 0; u < 8; ++u)
      p = fmaf(w2s[lane + 64 * u], qs[w * 512 + lane + 64 * u], p);
#pragma unroll
    for (int o = 32; o; o >>= 1) p += __shfl_xor(p, o, 64);
    if (lane == 0) qlin[w] = 0.505f * p;
  }
  __syncthreads();
  // compaction indices (must match gemm_k scan)
  bool act = false;
  int pre = 0;
  if (t < 256) {
    const int flag = sflag;
    const unsigned char* m8 = (const unsigned char*)maskp;
    const int* m32 = (const int*)maskp;
    act = flag ? (m8[b * 256 + t] == 0) : (m32[b * 256 + t] == 0);
    unsigned long long bal = __ballot(act);
    pre = __popcll(bal & ((1ull << lane) - 1ull));
    if (lane == 0) wsumS[w] = __popcll(bal);
  }
  __syncthreads();
  if (t < 256 && act) {
    int off = 0;
#pragma unroll
    for (int ww = 0; ww < 4; ++ww)
      if (ww < w) off += wsumS[ww];
    kidxS[off + pre] = t;
  }
  if (t == 0) nkS = wsumS[0] + wsumS[1] + wsumS[2] + wsumS[3];
  __syncthreads();
  const int nk = nkS;
  const int nc64 = (nk + 63) >> 6;

  // score loop: wave w -> h [w*64,+64), gang (lane>>4) -> 16-h slice;
  // lane owns 4 contiguous compacted cols. fp16 packed math, fp32 accum.
  {
    const int gang = lane >> 4, li = lane & 15;
    const int hbase = w * 64 + gang * 16;
    const unsigned* kTb = kT2 + (size_t)b * 256;
#pragma unroll 1
    for (int cb = 0; cb < nc64; ++cb) {
      const int colo = cb * 64 + li * 4;
      float sa[4][4] = {};  // [q][c]
      float kl4[4] = {};
#pragma unroll
      for (int hg = 0; hg < 4; ++hg) {
        const int h = hbase + hg * 4;
        const int hp = h >> 1;
        uint4 ua = *(const uint4*)&kTb[(size_t)hp * 1024 + colo];
        uint4 ub = *(const uint4*)&kTb[(size_t)(hp + 1) * 1024 + colo];
        uint2 wpp = *(const uint2*)&w2p[hp];
        half2v w01 = uh(wpp.x), w23 = uh(wpp.y);
        half2v q01[4], q23[4];
#pragma unroll
        for (int q = 0; q < 4; ++q) {
          uint2 qq = *(const uint2*)&qp[q * 256 + hp];
          q01[q] = uh(qq.x);
          q23[q] = uh(qq.y);
        }
        unsigned uac[4] = {ua.x, ua.y, ua.z, ua.w};
        unsigned ubc[4] = {ub.x, ub.y, ub.z, ub.w};
#pragma unroll
        for (int c = 0; c < 4; ++c) {
          half2v k01 = uh(uac[c]), k23 = uh(ubc[c]);
          kl4[c] = fdot2f(w01, k01, kl4[c]);
          kl4[c] = fdot2f(w23, k23, kl4[c]);
#pragma unroll
          for (int q = 0; q < 4; ++q) {
            sa[q][c] = fdot2f(w01, habs2(k01 + q01[q]), sa[q][c]);
            sa[q][c] = fdot2f(w23, habs2(k23 + q23[q]), sa[q][c]);
          }
        }
      }
      // cross-gang butterfly (lanes ^16, ^32)
#pragma unroll
      for (int q = 0; q < 4; ++q)
#pragma unroll
        for (int c = 0; c < 4; ++c) {
          sa[q][c] += __shfl_xor(sa[q][c], 16, 64);
          sa[q][c] += __shfl_xor(sa[q][c], 32, 64);
        }
#pragma unroll
      for (int c = 0; c < 4; ++c) {
        kl4[c] += __shfl_xor(kl4[c], 16, 64);
        kl4[c] += __shfl_xor(kl4[c], 32, 64);
      }
      if (gang == 0) {
#pragma unroll
        for (int q = 0; q < 4; ++q)
          *(float4*)&sabs[(w * 4 + q) * 260 + colo] =
              make_float4(sa[q][0], sa[q][1], sa[q][2], sa[q][3]);
        *(float4*)&klin[w * 260 + colo] =
            make_float4(kl4[0], kl4[1], kl4[2], kl4[3]);
      }
    }
  }
  __syncthreads();
  // init att to -1e9
  if (t < 256) {
#pragma unroll
    for (int q = 0; q < 4; ++q) att[q * 260 + t] = -1e9f;
  }
  __syncthreads();
  // scatter active scores
  if (t < nk) {
    const int realk = kidxS[t];
    float kls = 0.f;
#pragma unroll
    for (int ww = 0; ww < 8; ++ww) kls += klin[ww * 260 + t];
    kls *= 0.505f;
#pragma unroll
    for (int q = 0; q < 4; ++q) {
      float v = 0.f;
#pragma unroll
      for (int ww = 0; ww < 8; ++ww) v += sabs[(ww * 4 + q) * 260 + t];
      att[q * 260 + realk] = qlin[q] + kls + 0.495f * v;
    }
  }
  __syncthreads();
  // softmax: wave w<4 -> row w
  if (w < 4) {
    float m = -1e30f;
#pragma unroll
    for (int u = 0; u < 4; ++u) m = fmaxf(m, att[w * 260 + lane + 64 * u]);
#pragma unroll
    for (int o = 32; o; o >>= 1) m = fmaxf(m, __shfl_xor(m, o, 64));
    float ssum = 0.f;
#pragma unroll
    for (int u = 0; u < 4; ++u) {
      float e = __expf(att[w * 260 + lane + 64 * u] - m);
      att[w * 260 + lane + 64 * u] = e;
      ssum += e;
    }
#pragma unroll
    for (int o = 32; o; o >>= 1) ssum += __shfl_xor(ssum, o, 64);
    if (lane == 0) rowsum[w] = ssum;
  }
  __syncthreads();
  // PV over compacted k
  {
    const int v0 = lane * 4;
    const float* Vb = V + (size_t)b * 65536;
    float acc[4][4] = {};
    for (int i = w; i < nk; i += 8) {
      int k = kidxS[i];
      float4 vv = *(const float4*)&Vb[(size_t)k * 256 + v0];
      float aw[4];
#pragma unroll
      for (int q = 0; q < 4; ++q) aw[q] = att[q * 260 + k];
#pragma unroll
      for (int q = 0; q < 4; ++q) {
        acc[q][0] = fmaf(aw[q], vv.x, acc[q][0]);
        acc[q][1] = fmaf(aw[q], vv.y, acc[q][1]);
        acc[q][2] = fmaf(aw[q], vv.z, acc[q][2]);
        acc[q][3] = fmaf(aw[q], vv.w, acc[q][3]);
      }
    }
#pragma unroll
    for (int q = 0; q < 4; ++q)
      *(float4*)&red[(w * 4 + q) * 264 + v0] =
          make_float4(acc[q][0], acc[q][1], acc[q][2], acc[q][3]);
  }
  __syncthreads();
  // final reduce + normalize
#pragma unroll
  for (int s = 0; s < 2; ++s) {
    int id = t + s * 512;
    int row = id >> 8, col = id & 255;
    float v = 0.f;
#pragma unroll
    for (int g = 0; g < 8; ++g) v += red[(g * 4 + row) * 264 + col];
    out[((size_t)b * 256 + q4 * 4 + row) * 256 + col] = v / rowsum[row];
  }
}

extern "C" void kernel_launch(void* const* d_in, const int* in_sizes, int n_in,
                              void* d_out, int out_size, void* d_ws,
                              size_t ws_size, hipStream_t stream) {
  const float* Q = (const float*)d_in[0];
  const float* K = (const float*)d_in[1];
  const float* V = (const float*)d_in[2];
  const void* mask = d_in[3];
  const float* W1 = (const float*)d_in[4];
  const float* b1 = (const float*)d_in[5];
  const float* W2 = (const float*)d_in[6];
  float* ws = (float*)d_ws;
  float* hh = ws + HH_OFF;
  unsigned* kT2 = (unsigned*)(ws + KT_OFF);
  float* out = (float*)d_out;

  gemm_k<<<dim3(256), dim3(512), 0, stream>>>(Q, K, W1, b1, mask, hh, kT2);
  attn_k<<<dim3(256), dim3(512), 0, stream>>>(hh, kT2, V, mask, W2, out);
}